// Round 9
// baseline (163.571 us; speedup 1.0000x reference)
//
#include <hip/hip_runtime.h>
#include <math.h>

#define S_LEN 2048
#define DMODEL 512
#define HDIM 64
#define EPS_G 1e-8f

typedef __bf16 bf16x8 __attribute__((ext_vector_type(8)));
typedef __bf16 bf16x4 __attribute__((ext_vector_type(4)));
typedef float f32x4 __attribute__((ext_vector_type(4)));

// ---------------------------------------------------------------------------
// Kernel 0: one-shot f32->bf16 conversion of X, Wq|Wk|Wv (stacked), Wo.
// ---------------------------------------------------------------------------
__global__ __launch_bounds__(256) void cvt_kernel(
    const float* __restrict__ X, const float* __restrict__ Wq,
    const float* __restrict__ Wk, const float* __restrict__ Wv,
    const float* __restrict__ Wo,
    __bf16* __restrict__ Xb, __bf16* __restrict__ Wb, __bf16* __restrict__ Wob) {
  const int u = blockIdx.x * 256 + threadIdx.x;   // float4 unit, 786432 total
  const float* src; __bf16* dst; int off;
  if (u < 524288)      { src = X;  dst = Xb;          off = u; }
  else if (u < 589824) { src = Wq; dst = Wb;          off = u - 524288; }
  else if (u < 655360) { src = Wk; dst = Wb + 262144; off = u - 589824; }
  else if (u < 720896) { src = Wv; dst = Wb + 524288; off = u - 655360; }
  else                 { src = Wo; dst = Wob;         off = u - 720896; }
  const float4 v = *(const float4*)(src + (size_t)off * 4);
  bf16x4 o;
  o[0] = (__bf16)v.x; o[1] = (__bf16)v.y; o[2] = (__bf16)v.z; o[3] = (__bf16)v.w;
  *(bf16x4*)(dst + (size_t)off * 4) = o;
}

// ---------------------------------------------------------------------------
// Kernel 1: fused QKV projection.  R10 wave decomposition: each wave owns
// ALL 64 rows (4 A-frags) x col-unit nt==wv x all 3 W matrices.
// ---------------------------------------------------------------------------
__global__ __launch_bounds__(256, 2) void qkv_gemm(
    const __bf16* __restrict__ Xb, const __bf16* __restrict__ Wb,
    const float* __restrict__ bq, const float* __restrict__ bk, const float* __restrict__ bv,
    const int* __restrict__ pos,
    __bf16* __restrict__ Qh, __bf16* __restrict__ Kh, __bf16* __restrict__ Vt) {
  const int i0 = blockIdx.x << 6;
  const int h  = blockIdx.y;           // 0..7
  const int j0 = h << 6;

  __shared__ __bf16 Xs[64][72];
  __shared__ __bf16 Wls[3][64][72];

  const int tid = threadIdx.x;
  const int wv = tid >> 6, lane = tid & 63;
  const int l = lane & 15, seg = lane >> 4;
  const int sr = tid >> 2, sc = (tid & 3) << 4;

  f32x4 O[3][4];                       // [w][r4], rows r4*16+seg*4+reg, col wv*16+l
#pragma unroll
  for (int w = 0; w < 3; ++w)
#pragma unroll
    for (int r4 = 0; r4 < 4; ++r4) O[w][r4] = (f32x4){0.f, 0.f, 0.f, 0.f};

  bf16x8 xr0, xr1, wr[3][2];
#define LOADQKV(K0)                                                                   \
  {                                                                                   \
    const __bf16* xp = Xb + (size_t)(i0 + sr) * 512 + (K0) + sc;                      \
    xr0 = *(const bf16x8*)xp; xr1 = *(const bf16x8*)(xp + 8);                         \
    _Pragma("unroll")                                                                 \
    for (int w = 0; w < 3; ++w) {                                                     \
      const __bf16* wp = Wb + (size_t)w * 262144 + (size_t)(j0 + sr) * 512 + (K0) + sc;\
      wr[w][0] = *(const bf16x8*)wp; wr[w][1] = *(const bf16x8*)(wp + 8);             \
    }                                                                                 \
  }

  LOADQKV(0)
  for (int k0 = 0; k0 < 512; k0 += 64) {
    __syncthreads();
    *(bf16x8*)&Xs[sr][sc]     = xr0;
    *(bf16x8*)&Xs[sr][sc + 8] = xr1;
#pragma unroll
    for (int w = 0; w < 3; ++w) {
      *(bf16x8*)&Wls[w][sr][sc]     = wr[w][0];
      *(bf16x8*)&Wls[w][sr][sc + 8] = wr[w][1];
    }
    __syncthreads();
    if (k0 < 448) LOADQKV(k0 + 64)

    bf16x8 a0[4], a1[4];
#pragma unroll
    for (int r4 = 0; r4 < 4; ++r4) {
      a0[r4] = *(const bf16x8*)&Xs[r4 * 16 + l][seg * 8];
      a1[r4] = *(const bf16x8*)&Xs[r4 * 16 + l][seg * 8 + 32];
    }
#pragma unroll
    for (int w = 0; w < 3; ++w) {
      bf16x8 b0 = *(const bf16x8*)&Wls[w][wv * 16 + l][seg * 8];
      bf16x8 b1 = *(const bf16x8*)&Wls[w][wv * 16 + l][seg * 8 + 32];
#pragma unroll
      for (int r4 = 0; r4 < 4; ++r4) {
        O[w][r4] = __builtin_amdgcn_mfma_f32_16x16x32_bf16(a0[r4], b0, O[w][r4], 0, 0, 0);
        O[w][r4] = __builtin_amdgcn_mfma_f32_16x16x32_bf16(a1[r4], b1, O[w][r4], 0, 0, 0);
      }
    }
  }

  // bias (col d = wv*16+l fixed per thread)
  const int d = wv * 16 + l;
  const float bbq = bq[j0 + d], bbk = bk[j0 + d], bbv = bv[j0 + d];
#pragma unroll
  for (int r4 = 0; r4 < 4; ++r4)
#pragma unroll
    for (int reg = 0; reg < 4; ++reg) {
      O[0][r4][reg] += bbq; O[1][r4][reg] += bbk; O[2][r4][reg] += bbv;
    }

  const int n = i0 >> 11, sb = i0 & 2047;
  const int nh = (n << 3) + h;

  // xpos constants: single (kp) per thread since nt==wv
  const float kp   = (float)(d >> 1);
  const float invf = exp2f(-0.41524100f * kp) * 0.15915494f;  // rev / unit pos
  const float l2sv = log2f((2.f * kp + 25.6f) * (1.f / 89.6f));
  float pv_[4][4];
#pragma unroll
  for (int r4 = 0; r4 < 4; ++r4)
#pragma unroll
    for (int reg = 0; reg < 4; ++reg)
      pv_[r4][reg] = (float)pos[n * S_LEN + sb + r4 * 16 + (seg << 2) + reg];

  __syncthreads();   // last MFMA reads done; Xs/Wls become epilogue bounces

#pragma unroll
  for (int r4 = 0; r4 < 4; ++r4)
#pragma unroll
    for (int reg = 0; reg < 4; ++reg) {
      const int row = r4 * 16 + (seg << 2) + reg;
      const float p = pv_[r4][reg];
      const float rev0 = p * invf;
      const float rev  = rev0 - floorf(rev0);
      const float sn = __builtin_amdgcn_sinf(rev);
      const float cn = __builtin_amdgcn_cosf(rev);
      const float sq = exp2f(p * (1.f / 512.f) * l2sv);
      const float sQ = sq * 0.125f;                   // fused HEAD_DIM^-0.5
      const float sK = __builtin_amdgcn_rcpf(sq);     // downscale for K
      float x  = O[0][r4][reg];
      float xp = __shfl_xor(x, 1);
      Xs[row][d] = (__bf16)((((d & 1) ? (x * cn + xp * sn) : (x * cn - xp * sn))) * sQ);
      x  = O[1][r4][reg];
      xp = __shfl_xor(x, 1);
      Wls[0][row][d] = (__bf16)((((d & 1) ? (x * cn + xp * sn) : (x * cn - xp * sn))) * sK);
      Wls[1][row][d] = (__bf16)O[2][r4][reg];
    }
  __syncthreads();

  __bf16* qdst = Qh + (((size_t)nh * S_LEN + sb + sr) << 6) + sc;
  *(bf16x8*)qdst       = *(bf16x8*)&Xs[sr][sc];
  *(bf16x8*)(qdst + 8) = *(bf16x8*)&Xs[sr][sc + 8];
  __bf16* kdst = Kh + (((size_t)nh * S_LEN + sb + sr) << 6) + sc;
  *(bf16x8*)kdst       = *(bf16x8*)&Wls[0][sr][sc];
  *(bf16x8*)(kdst + 8) = *(bf16x8*)&Wls[0][sr][sc + 8];

  const int dv = tid >> 2, part = tid & 3;
  __bf16 tmp[16];
#pragma unroll
  for (int i = 0; i < 16; ++i) tmp[i] = Wls[1][part * 16 + i][dv];
  __bf16* vdst = Vt + (((size_t)(nh * 64 + dv)) << 11) + sb + part * 16;
  *(bf16x8*)vdst       = *(bf16x8*)&tmp[0];
  *(bf16x8*)(vdst + 8) = *(bf16x8*)&tmp[8];
}

// ---------------------------------------------------------------------------
// Kernel 2: sigmoid-gated attention, split-K chunks.
// R18 (resubmit after R8 infra failure): exact R13 body (proven 43.4us) —
// R14 dbuf, R15/R16 fused-combine, R17 2-tile ILP all regressed/failed and
// are reverted.  Only deltas:
// (a) __launch_bounds__(256,4): raises compiler waves/EU floor; VGPR 76 is
//     well under the 128 budget so codegen is unchanged — tests whether the
//     persistent ~2-block residency was a compiler-request artifact.
// (b) f = (1+eps) - a fold (hipcc won't reassociate FP; -16 VALU/tile).
// ---------------------------------------------------------------------------
__global__ __launch_bounds__(256, 4) void attn_chunk(
    const __bf16* __restrict__ Qh, const __bf16* __restrict__ Kh,
    const __bf16* __restrict__ Vt, const float* __restrict__ imask,
    __bf16* __restrict__ att, float* __restrict__ PartO,
    float* __restrict__ PartP, float* __restrict__ PartA0) {
  const int id = 1279 - (int)blockIdx.x;   // longest chunks first (LPT)
  const int nh = id & 15;
  const int t  = id >> 4;              // 0..79 chunk id within head
  int rb, c, nc;
  if (t < 8)       { rb = t; c = 0; nc = 1; }
  else if (t < 24) { int u = t - 8;  rb = 8  + (u >> 1); c = u & 1;     nc = 2; }
  else if (t < 48) { int u = t - 24; rb = 16 + u / 3;    c = u - 3 * (u / 3); nc = 3; }
  else             { int u = t - 48; rb = 24 + (u >> 2); c = u & 3;     nc = 4; }
  // equal split of T = rb+1 tiles into nc chunks; c=0 is the TOP chunk
  const int T   = rb + 1;
  const int bsz = T / nc;
  const int rem = T - bsz * nc;
  const int szc  = bsz + ((c < rem) ? 1 : 0);
  const int skip = c * bsz + ((c < rem) ? c : rem);
  const int hi = rb - skip;
  const int lo = hi - szc + 1;         // == 0 for c == nc-1

  const int n = nh >> 3, h = nh & 7;
  const int tid = threadIdx.x;
  const int wv = tid >> 6, lane = tid & 63;
  const int l = lane & 15, seg = lane >> 4;
  const int sg4 = seg << 2;
  const int pr = tid >> 3, pc = (tid & 7) << 3;

  __shared__ __bf16 Ks16[64][72];
  __shared__ __bf16 Vt16[64][72];
  __shared__ __bf16 cs16[64][72];      // C^T per wave: rows wv*16+l = q, cols = key
  __shared__ float msk[64];
  __shared__ float v0buf[64];          // V[k0][d] for current tile

  // Q frags: loop-invariant, thread's q = wv*16+l (used as MFMA B operand).
  const __bf16* qbase =
      Qh + (((size_t)nh * S_LEN + rb * 64 + wv * 16 + l) << 6);
  const bf16x8 aq0 = *(const bf16x8*)(qbase + seg * 8);
  const bf16x8 aq1 = *(const bf16x8*)(qbase + seg * 8 + 32);

  f32x4 O[4];                          // O^T: row d = dblk*16+sg4+reg, col q=l
  f32x4 pend[4];
  float Crow = 1.f;
  float a0k0 = 0.f;
#pragma unroll
  for (int d_ = 0; d_ < 4; ++d_) {
    O[d_] = (f32x4){0.f, 0.f, 0.f, 0.f};
    pend[d_] = (f32x4){0.f, 0.f, 0.f, 0.f};
  }

  bf16x8 kp0, kp1, vp0, vp1;
  float mp = 0.f;
#define LOADKV(JT)                                                                     \
  kp0 = *(const bf16x8*)(Kh + (((size_t)nh * S_LEN + (JT) * 64 + pr) << 6) + pc);      \
  kp1 = *(const bf16x8*)(Kh + (((size_t)nh * S_LEN + (JT) * 64 + 32 + pr) << 6) + pc); \
  vp0 = *(const bf16x8*)(Vt + (((size_t)(nh * 64 + pr)) << 11) + (JT) * 64 + pc);      \
  vp1 = *(const bf16x8*)(Vt + (((size_t)(nh * 64 + 32 + pr)) << 11) + (JT) * 64 + pc); \
  if (tid < 64) mp = imask[n * S_LEN + (JT) * 64 + tid];

  LOADKV(hi)

  for (int jt = hi; jt >= lo; --jt) {
    __syncthreads();
    *(bf16x8*)&Ks16[pr][pc]      = kp0;
    *(bf16x8*)&Ks16[32 + pr][pc] = kp1;
    *(bf16x8*)&Vt16[pr][pc]      = vp0;
    *(bf16x8*)&Vt16[32 + pr][pc] = vp1;
    if (tid < 64) msk[tid] = mp;
    if ((tid & 7) == 0) {                      // pc == 0 threads hold k-offset 0
      v0buf[pr]      = (float)vp0[0];
      v0buf[32 + pr] = (float)vp1[0];
    }
    __syncthreads();
    if (jt > lo) { LOADKV(jt - 1) }

    // ---- QK^T (transposed: A=K rows, B=Q) -> S^T[key][q] ----
    f32x4 Sv[4];
    __builtin_amdgcn_s_setprio(1);
#pragma unroll
    for (int nt = 0; nt < 4; ++nt) {
      bf16x8 bk0 = *(const bf16x8*)&Ks16[nt * 16 + l][seg * 8];
      bf16x8 bk1 = *(const bf16x8*)&Ks16[nt * 16 + l][seg * 8 + 32];
      f32x4 z = (f32x4){0.f, 0.f, 0.f, 0.f};
      z = __builtin_amdgcn_mfma_f32_16x16x32_bf16(bk0, aq0, z, 0, 0, 0);
      z = __builtin_amdgcn_mfma_f32_16x16x32_bf16(bk1, aq1, z, 0, 0, 0);
      Sv[nt] = z;
    }
    __builtin_amdgcn_s_setprio(0);

    const bool diag = (jt == rb);        // wave-uniform: only c==0 first tile
    const int qoff = wv * 16 + l;        // local query row of this thread

    // ---- gates ----
    float a_[4][4];
#pragma unroll
    for (int nt = 0; nt < 4; ++nt) {
      const float4 m4 = *(const float4*)&msk[nt * 16 + sg4];
      a_[nt][0] = m4.x * __builtin_amdgcn_rcpf(1.f + __expf(-Sv[nt][0]));
      a_[nt][1] = m4.y * __builtin_amdgcn_rcpf(1.f + __expf(-Sv[nt][1]));
      a_[nt][2] = m4.z * __builtin_amdgcn_rcpf(1.f + __expf(-Sv[nt][2]));
      a_[nt][3] = m4.w * __builtin_amdgcn_rcpf(1.f + __expf(-Sv[nt][3]));
    }
    if (diag) {
#pragma unroll
      for (int nt = 0; nt < 4; ++nt)
#pragma unroll
        for (int reg = 0; reg < 4; ++reg)
          if (nt * 16 + sg4 + reg > qoff) a_[nt][reg] = 0.f;
    }

    // ---- in-register suffix products over keys ----
    const float ONE_EPS = 1.f + EPS_G;
    float t_[4][4], gp[4], f3s[4];
#pragma unroll
    for (int nt = 0; nt < 4; ++nt) {
      const float f0 = ONE_EPS - a_[nt][0];
      const float f1 = ONE_EPS - a_[nt][1];
      const float f2 = ONE_EPS - a_[nt][2];
      const float f3 = ONE_EPS - a_[nt][3];
      t_[nt][3] = f3;
      t_[nt][2] = f2 * f3;
      t_[nt][1] = f1 * t_[nt][2];
      t_[nt][0] = f0 * t_[nt][1];
      gp[nt] = t_[nt][0];
      f3s[nt] = f3;
    }

    // ---- cross-seg gathers (per 16-key chunk) ----
    float S_[4], GP[4], Xs_[4], Yb[4];
#pragma unroll
    for (int nt = 0; nt < 4; ++nt) {
      const float b = __shfl_xor(gp[nt], 16);   // gp[seg^1]
      const float cc = __shfl_xor(gp[nt], 32);  // gp[seg^2]
      const float dd = __shfl_xor(b, 32);       // gp[seg^3]
      const float cd = cc * dd;
      const float low  = (seg & 1) ? cd : b * cd;   // seg0: bcd, seg1: cd
      const float high = (seg & 1) ? 1.f : b;       // seg2: b,  seg3: 1
      S_[nt] = (seg & 2) ? high : low;          // prod of gp over segs > seg
      GP[nt] = gp[nt] * b * cd;                 // full 16-chunk product
      Xs_[nt] = __shfl_up(f3s[nt], 16);         // f tail of seg-1 (seg>=1)
      Yb[nt] = __shfl(f3s[nt], 48 + l);         // f tail of chunk (seg3), bcast
    }
    const float T2 = GP[3], T1 = T2 * GP[2], T0 = T1 * GP[1];
    const float Tarr[4] = {T0, T1, T2, 1.f};
    const float Ptile = T0 * GP[0];
    const float A0 = __shfl(a_[0][0], l);       // gate of tile key 0, bcast

    // ---- coefficients: cv(key j) = a_j * f_{j-1} * sfx(j) * Crow ----
#pragma unroll
    for (int nt = 0; nt < 4; ++nt) {
      const float wc = S_[nt] * Tarr[nt] * Crow;
      float cv0 = a_[nt][0] * Xs_[nt] * gp[nt] * wc;       // seg>=1 path
      const float cv0s0 = (nt == 0)
          ? ((jt == 0 && nc == 1) ? a_[0][0] : 0.f)        // key 0: direct / pend
          : a_[nt][0] * Yb[nt - 1] * Tarr[nt - 1] * Crow;  // chunk boundary
      if (seg == 0) cv0 = cv0s0;
      const float cv1 = a_[nt][1] * t_[nt][0] * wc;
      const float cv2 = a_[nt][2] * t_[nt][1] * wc;
      const float cv3 = a_[nt][3] * t_[nt][2] * wc;
      bf16x4 pk;
      pk[0] = (__bf16)cv0; pk[1] = (__bf16)cv1;
      pk[2] = (__bf16)cv2; pk[3] = (__bf16)cv3;
      *(bf16x4*)&cs16[wv * 16 + l][nt * 16 + sg4] = pk;
    }

    // ---- pending rank-1 term (key0 of this tile resolves next tile) ----
    const float f63 = Yb[3];
    const float s0 = A0 * Ptile * Crow;
    Crow *= Ptile;
    if (jt == 0) a0k0 = A0;
#pragma unroll
    for (int dblk = 0; dblk < 4; ++dblk) {
      O[dblk][0] += pend[dblk][0] * f63;
      O[dblk][1] += pend[dblk][1] * f63;
      O[dblk][2] += pend[dblk][2] * f63;
      O[dblk][3] += pend[dblk][3] * f63;
      const float4 v4 = *(const float4*)&v0buf[dblk * 16 + sg4];
      pend[dblk][0] = s0 * v4.x; pend[dblk][1] = s0 * v4.y;
      pend[dblk][2] = s0 * v4.z; pend[dblk][3] = s0 * v4.w;
    }

    // ---- PV (transposed: A=V^T rows d, B=C^T) -> O^T ----
    bf16x8 bc0 = *(const bf16x8*)&cs16[wv * 16 + l][seg * 8];
    bf16x8 bc1 = *(const bf16x8*)&cs16[wv * 16 + l][seg * 8 + 32];
    __builtin_amdgcn_s_setprio(1);
#pragma unroll
    for (int dblk = 0; dblk < 4; ++dblk) {
      bf16x8 av0 = *(const bf16x8*)&Vt16[dblk * 16 + l][seg * 8];
      bf16x8 av1 = *(const bf16x8*)&Vt16[dblk * 16 + l][seg * 8 + 32];
      O[dblk] = __builtin_amdgcn_mfma_f32_16x16x32_bf16(av0, bc0, O[dblk], 0, 0, 0);
      O[dblk] = __builtin_amdgcn_mfma_f32_16x16x32_bf16(av1, bc1, O[dblk], 0, 0, 0);
    }
    __builtin_amdgcn_s_setprio(0);
  }

  // ---- low-boundary pending resolution (chunk does not reach key 0) ----
  if (lo > 0) {
    const int m = lo << 6;
    const float mb = imask[n * S_LEN + m - 1];
    const __bf16* kb = Kh + (((size_t)nh * S_LEN + m - 1) << 6) + seg * 16;
    bf16x8 kb0 = *(const bf16x8*)kb, kb1 = *(const bf16x8*)(kb + 8);
    bf16x8 q0 = *(const bf16x8*)(qbase + seg * 16);
    bf16x8 q1 = *(const bf16x8*)(qbase + seg * 16 + 8);
    float sc_ = 0.f;
#pragma unroll
    for (int j = 0; j < 8; ++j)
      sc_ += (float)q0[j] * (float)kb0[j] + (float)q1[j] * (float)kb1[j];
    sc_ += __shfl_xor(sc_, 16);
    sc_ += __shfl_xor(sc_, 32);
    const float fbl = 1.f - mb * __builtin_amdgcn_rcpf(1.f + __expf(-sc_)) + EPS_G;
#pragma unroll
    for (int dblk = 0; dblk < 4; ++dblk) {
      O[dblk][0] += pend[dblk][0] * fbl;
      O[dblk][1] += pend[dblk][1] * fbl;
      O[dblk][2] += pend[dblk][2] * fbl;
      O[dblk][3] += pend[dblk][3] * fbl;
    }
  }

  if (nc == 1) {
    __bf16* arow = att + ((size_t)(n * S_LEN + rb * 64 + wv * 16 + l)) * DMODEL + h * HDIM;
#pragma unroll
    for (int dblk = 0; dblk < 4; ++dblk) {
      bf16x4 ob;
      ob[0] = (__bf16)O[dblk][0]; ob[1] = (__bf16)O[dblk][1];
      ob[2] = (__bf16)O[dblk][2]; ob[3] = (__bf16)O[dblk][3];
      *(bf16x4*)(arow + dblk * 16 + sg4) = ob;
    }
  } else {
    const int slot = nh * 72 + (t - 8);
    float* po = PartO + (size_t)slot * 4096 + (wv * 16 + l) * 64;
#pragma unroll
    for (int dblk = 0; dblk < 4; ++dblk) {
      float4 v;
      v.x = O[dblk][0]; v.y = O[dblk][1]; v.z = O[dblk][2]; v.w = O[dblk][3];
      *(float4*)(po + dblk * 16 + sg4) = v;
    }
    if (seg == 0) {
      PartP[slot * 64 + wv * 16 + l] = Crow;
      if (lo == 0)
        PartA0[(nh * 24 + rb - 8) * 64 + wv * 16 + l] = a0k0;
    }
  }
}

// ---------------------------------------------------------------------------
// Kernel 3: combine chunk partials: O = sum_c (prod_{c'<c} P_c') O_c + a0 (x) V0
// ---------------------------------------------------------------------------
__global__ __launch_bounds__(256) void combine_kernel(
    const float* __restrict__ PartO, const float* __restrict__ PartP,
    const float* __restrict__ PartA0, const __bf16* __restrict__ Vt,
    __bf16* __restrict__ att) {
  const int b = blockIdx.x;            // 16 x 24
  const int nh = b / 24;
  const int rb = 8 + (b - nh * 24);
  const int nc = (rb < 16) ? 2 : ((rb < 24) ? 3 : 4);
  const int t0 = (rb < 16) ? 8 + ((rb - 8) << 1)
               : (rb < 24) ? 24 + (rb - 16) * 3
                           : 48 + ((rb - 24) << 2);
  const int n = nh >> 3, h = nh & 7;
  const int tid = threadIdx.x;
  const int r = tid >> 2, db = (tid & 3) << 4;

  float acc[16];
#pragma unroll
  for (int j = 0; j < 16; ++j) acc[j] = 0.f;
  float fac = 1.f;
  for (int c = 0; c < nc; ++c) {
    const int slot = nh * 72 + (t0 - 8) + c;
    const float* po = PartO + (size_t)slot * 4096 + r * 64 + db;
    const float P = PartP[slot * 64 + r];
#pragma unroll
    for (int q = 0; q < 4; ++q) {
      const float4 v = *(const float4*)(po + q * 4);
      acc[q * 4 + 0] += fac * v.x; acc[q * 4 + 1] += fac * v.y;
      acc[q * 4 + 2] += fac * v.z; acc[q * 4 + 3] += fac * v.w;
    }
    fac *= P;
  }
  const float a0 = PartA0[(nh * 24 + rb - 8) * 64 + r];
#pragma unroll
  for (int j = 0; j < 16; ++j)
    acc[j] += a0 * (float)Vt[(((size_t)(nh * 64 + db + j)) << 11)];

  __bf16 ob[16];
#pragma unroll
  for (int j = 0; j < 16; ++j) ob[j] = (__bf16)acc[j];
  __bf16* dst = att + ((size_t)(n * S_LEN + rb * 64 + r)) * DMODEL + h * HDIM + db;
  *(bf16x8*)dst       = *(bf16x8*)&ob[0];
  *(bf16x8*)(dst + 8) = *(bf16x8*)&ob[8];
}

// ---------------------------------------------------------------------------
// Kernel 4: out = att @ Wo^T + bo.  R10 wave decomposition: wave owns all
// 64 rows (4 A-frags) x units {wv, wv+4}: 16 MFMAs / 12 LDS reads per k-iter.
// ---------------------------------------------------------------------------
__global__ __launch_bounds__(256, 2) void out_gemm(const __bf16* __restrict__ Xa,
                                                   const __bf16* __restrict__ Wob,
                                                   const float* __restrict__ bo,
                                                   float* __restrict__ Out) {
  const int i0 = blockIdx.x << 6, j0 = blockIdx.y << 7;
  __shared__ __bf16 As[64][72];
  __shared__ __bf16 Bs[128][72];

  const int tid = threadIdx.x;
  const int wv = tid >> 6, lane = tid & 63;
  const int l = lane & 15, seg = lane >> 4;
  const int sr = tid >> 2, sc = (tid & 3) << 4;

  f32x4 O[2][4];                       // [j][r4]; unit u = wv + 4*j
#pragma unroll
  for (int j = 0; j < 2; ++j)
#pragma unroll
    for (int r4 = 0; r4 < 4; ++r4) O[j][r4] = (f32x4){0.f, 0.f, 0.f, 0.f};

  bf16x8 ar0, ar1, br[2][2];
#define LOADOUT(K0)                                                          \
  {                                                                          \
    const __bf16* xp = Xa + (size_t)(i0 + sr) * 512 + (K0) + sc;             \
    ar0 = *(const bf16x8*)xp; ar1 = *(const bf16x8*)(xp + 8);                \
    _Pragma("unroll")                                                        \
    for (int ps = 0; ps < 2; ++ps) {                                         \
      const __bf16* wp = Wob + (size_t)(j0 + ps * 64 + sr) * 512 + (K0) + sc;\
      br[ps][0] = *(const bf16x8*)wp; br[ps][1] = *(const bf16x8*)(wp + 8);  \
    }                                                                        \
  }

  LOADOUT(0)
  for (int k0 = 0; k0 < 512; k0 += 64) {
    __syncthreads();
    *(bf16x8*)&As[sr][sc]     = ar0;
    *(bf16x8*)&As[sr][sc + 8] = ar1;
#pragma unroll
    for (int ps = 0; ps < 2; ++ps) {
      *(bf16x8*)&Bs[ps * 64 + sr][sc]     = br[ps][0];
      *(bf16x8*)&Bs[ps * 64 + sr][sc + 8] = br[ps][1];
    }
    __syncthreads();
    if (k0 < 448) LOADOUT(k0 + 64)

    bf16x8 a0[4], a1[4];
#pragma unroll
    for (int r4 = 0; r4 < 4; ++r4) {
      a0[r4] = *(const bf16x8*)&As[r4 * 16 + l][seg * 8];
      a1[r4] = *(const bf16x8*)&As[r4 * 16 + l][seg * 8 + 32];
    }
#pragma unroll
    for (int j = 0; j < 2; ++j) {
      const int u = wv + 4 * j;
      bf16x8 b0 = *(const bf16x8*)&Bs[u * 16 + l][seg * 8];
      bf16x8 b1 = *(const bf16x8*)&Bs[u * 16 + l][seg * 8 + 32];
#pragma unroll
      for (int r4 = 0; r4 < 4; ++r4) {
        O[j][r4] = __builtin_amdgcn_mfma_f32_16x16x32_bf16(a0[r4], b0, O[j][r4], 0, 0, 0);
        O[j][r4] = __builtin_amdgcn_mfma_f32_16x16x32_bf16(a1[r4], b1, O[j][r4], 0, 0, 0);
      }
    }
  }

#pragma unroll
  for (int j = 0; j < 2; ++j) {
    const int u = wv + 4 * j;
    const float bb = bo[j0 + u * 16 + l];
#pragma unroll
    for (int r4 = 0; r4 < 4; ++r4)
#pragma unroll
      for (int reg = 0; reg < 4; ++reg) {
        const int m = r4 * 16 + (seg << 2) + reg;
        Out[(size_t)(i0 + m) * 512 + j0 + u * 16 + l] = O[j][r4][reg] + bb;
      }
  }
}

// ---------------------------------------------------------------------------
extern "C" void kernel_launch(void* const* d_in, const int* in_sizes, int n_in,
                              void* d_out, int out_size, void* d_ws, size_t ws_size,
                              hipStream_t stream) {
  (void)in_sizes; (void)n_in; (void)out_size; (void)ws_size;
  const float* seq  = (const float*)d_in[0];
  const float* mask = (const float*)d_in[1];
  const int*   pos  = (const int*)d_in[2];
  const float* Wq = (const float*)d_in[4];
  const float* bq = (const float*)d_in[5];
  const float* Wk = (const float*)d_in[6];
  const float* bk = (const float*)d_in[7];
  const float* Wv = (const float*)d_in[8];
  const float* bv = (const float*)d_in[9];
  const float* Wo = (const float*)d_in[10];
  const float* bo = (const float*)d_in[11];
  float* out = (float*)d_out;

  char* base = (char*)d_ws;
  __bf16* att = (__bf16*)base;                     // 4 MB  (4096 x 512 bf16)
  __bf16* Qh  = (__bf16*)(base + ( 4u << 20));     // 4 MB
  __bf16* Kh  = (__bf16*)(base + ( 8u << 20));     // 4 MB
  __bf16* Vt  = (__bf16*)(base + (12u << 20));     // 4 MB  [nh][d][2048]
  __bf16* Wb  = (__bf16*)(base + (16u << 20));     // 1.5 MB
  __bf16* Wob = (__bf16*)(base + (18u << 20));     // 0.5 MB
  __bf16* Xb  = (__bf16*)(base + (19u << 20));     // 4 MB  (dead after qkv)
  float* PartO  = (float*)(base + (23u << 20));    // 16*72*4096*4 = 18.9 MB
  float* PartP  = (float*)(base + (42u << 20));    // 16*72*64*4   = 295 KB
  float* PartA0 = (float*)(base + (43u << 20));    // 16*24*64*4   = 98 KB

  cvt_kernel<<<3072, 256, 0, stream>>>(seq, Wq, Wk, Wv, Wo, Xb, Wb, Wob);
  qkv_gemm<<<dim3(64, 8), 256, 0, stream>>>(Xb, Wb, bq, bk, bv, pos, Qh, Kh, Vt);
  attn_chunk<<<1280, 256, 0, stream>>>(Qh, Kh, Vt, mask, att, PartO, PartP, PartA0);
  combine_kernel<<<384, 256, 0, stream>>>(PartO, PartP, PartA0, Vt, att);
  out_gemm<<<dim3(64, 4), 256, 0, stream>>>(att, Wob, bo, out);
}

// Round 10
// 148.212 us; speedup vs baseline: 1.1036x; 1.1036x over previous
//
#include <hip/hip_runtime.h>
#include <math.h>

#define S_LEN 2048
#define DMODEL 512
#define HDIM 64
#define EPS_G 1e-8f

typedef __bf16 bf16x8 __attribute__((ext_vector_type(8)));
typedef __bf16 bf16x4 __attribute__((ext_vector_type(4)));
typedef float f32x4 __attribute__((ext_vector_type(4)));

// ---------------------------------------------------------------------------
// Kernel 0: one-shot f32->bf16 conversion of X, Wq|Wk|Wv (stacked), Wo.
// ---------------------------------------------------------------------------
__global__ __launch_bounds__(256) void cvt_kernel(
    const float* __restrict__ X, const float* __restrict__ Wq,
    const float* __restrict__ Wk, const float* __restrict__ Wv,
    const float* __restrict__ Wo,
    __bf16* __restrict__ Xb, __bf16* __restrict__ Wb, __bf16* __restrict__ Wob) {
  const int u = blockIdx.x * 256 + threadIdx.x;   // float4 unit, 786432 total
  const float* src; __bf16* dst; int off;
  if (u < 524288)      { src = X;  dst = Xb;          off = u; }
  else if (u < 589824) { src = Wq; dst = Wb;          off = u - 524288; }
  else if (u < 655360) { src = Wk; dst = Wb + 262144; off = u - 589824; }
  else if (u < 720896) { src = Wv; dst = Wb + 524288; off = u - 655360; }
  else                 { src = Wo; dst = Wob;         off = u - 720896; }
  const float4 v = *(const float4*)(src + (size_t)off * 4);
  bf16x4 o;
  o[0] = (__bf16)v.x; o[1] = (__bf16)v.y; o[2] = (__bf16)v.z; o[3] = (__bf16)v.w;
  *(bf16x4*)(dst + (size_t)off * 4) = o;
}

// ---------------------------------------------------------------------------
// Kernel 1: fused QKV projection.  R10 wave decomposition: each wave owns
// ALL 64 rows (4 A-frags) x col-unit nt==wv x all 3 W matrices.
// ---------------------------------------------------------------------------
__global__ __launch_bounds__(256, 2) void qkv_gemm(
    const __bf16* __restrict__ Xb, const __bf16* __restrict__ Wb,
    const float* __restrict__ bq, const float* __restrict__ bk, const float* __restrict__ bv,
    const int* __restrict__ pos,
    __bf16* __restrict__ Qh, __bf16* __restrict__ Kh, __bf16* __restrict__ Vt) {
  const int i0 = blockIdx.x << 6;
  const int h  = blockIdx.y;           // 0..7
  const int j0 = h << 6;

  __shared__ __bf16 Xs[64][72];
  __shared__ __bf16 Wls[3][64][72];

  const int tid = threadIdx.x;
  const int wv = tid >> 6, lane = tid & 63;
  const int l = lane & 15, seg = lane >> 4;
  const int sr = tid >> 2, sc = (tid & 3) << 4;

  f32x4 O[3][4];                       // [w][r4], rows r4*16+seg*4+reg, col wv*16+l
#pragma unroll
  for (int w = 0; w < 3; ++w)
#pragma unroll
    for (int r4 = 0; r4 < 4; ++r4) O[w][r4] = (f32x4){0.f, 0.f, 0.f, 0.f};

  bf16x8 xr0, xr1, wr[3][2];
#define LOADQKV(K0)                                                                   \
  {                                                                                   \
    const __bf16* xp = Xb + (size_t)(i0 + sr) * 512 + (K0) + sc;                      \
    xr0 = *(const bf16x8*)xp; xr1 = *(const bf16x8*)(xp + 8);                         \
    _Pragma("unroll")                                                                 \
    for (int w = 0; w < 3; ++w) {                                                     \
      const __bf16* wp = Wb + (size_t)w * 262144 + (size_t)(j0 + sr) * 512 + (K0) + sc;\
      wr[w][0] = *(const bf16x8*)wp; wr[w][1] = *(const bf16x8*)(wp + 8);             \
    }                                                                                 \
  }

  LOADQKV(0)
  for (int k0 = 0; k0 < 512; k0 += 64) {
    __syncthreads();
    *(bf16x8*)&Xs[sr][sc]     = xr0;
    *(bf16x8*)&Xs[sr][sc + 8] = xr1;
#pragma unroll
    for (int w = 0; w < 3; ++w) {
      *(bf16x8*)&Wls[w][sr][sc]     = wr[w][0];
      *(bf16x8*)&Wls[w][sr][sc + 8] = wr[w][1];
    }
    __syncthreads();
    if (k0 < 448) LOADQKV(k0 + 64)

    bf16x8 a0[4], a1[4];
#pragma unroll
    for (int r4 = 0; r4 < 4; ++r4) {
      a0[r4] = *(const bf16x8*)&Xs[r4 * 16 + l][seg * 8];
      a1[r4] = *(const bf16x8*)&Xs[r4 * 16 + l][seg * 8 + 32];
    }
#pragma unroll
    for (int w = 0; w < 3; ++w) {
      bf16x8 b0 = *(const bf16x8*)&Wls[w][wv * 16 + l][seg * 8];
      bf16x8 b1 = *(const bf16x8*)&Wls[w][wv * 16 + l][seg * 8 + 32];
#pragma unroll
      for (int r4 = 0; r4 < 4; ++r4) {
        O[w][r4] = __builtin_amdgcn_mfma_f32_16x16x32_bf16(a0[r4], b0, O[w][r4], 0, 0, 0);
        O[w][r4] = __builtin_amdgcn_mfma_f32_16x16x32_bf16(a1[r4], b1, O[w][r4], 0, 0, 0);
      }
    }
  }

  // bias (col d = wv*16+l fixed per thread)
  const int d = wv * 16 + l;
  const float bbq = bq[j0 + d], bbk = bk[j0 + d], bbv = bv[j0 + d];
#pragma unroll
  for (int r4 = 0; r4 < 4; ++r4)
#pragma unroll
    for (int reg = 0; reg < 4; ++reg) {
      O[0][r4][reg] += bbq; O[1][r4][reg] += bbk; O[2][r4][reg] += bbv;
    }

  const int n = i0 >> 11, sb = i0 & 2047;
  const int nh = (n << 3) + h;

  // xpos constants: single (kp) per thread since nt==wv
  const float kp   = (float)(d >> 1);
  const float invf = exp2f(-0.41524100f * kp) * 0.15915494f;  // rev / unit pos
  const float l2sv = log2f((2.f * kp + 25.6f) * (1.f / 89.6f));
  float pv_[4][4];
#pragma unroll
  for (int r4 = 0; r4 < 4; ++r4)
#pragma unroll
    for (int reg = 0; reg < 4; ++reg)
      pv_[r4][reg] = (float)pos[n * S_LEN + sb + r4 * 16 + (seg << 2) + reg];

  __syncthreads();   // last MFMA reads done; Xs/Wls become epilogue bounces

#pragma unroll
  for (int r4 = 0; r4 < 4; ++r4)
#pragma unroll
    for (int reg = 0; reg < 4; ++reg) {
      const int row = r4 * 16 + (seg << 2) + reg;
      const float p = pv_[r4][reg];
      const float rev0 = p * invf;
      const float rev  = rev0 - floorf(rev0);
      const float sn = __builtin_amdgcn_sinf(rev);
      const float cn = __builtin_amdgcn_cosf(rev);
      const float sq = exp2f(p * (1.f / 512.f) * l2sv);
      const float sQ = sq * 0.125f;                   // fused HEAD_DIM^-0.5
      const float sK = __builtin_amdgcn_rcpf(sq);     // downscale for K
      float x  = O[0][r4][reg];
      float xp = __shfl_xor(x, 1);
      Xs[row][d] = (__bf16)((((d & 1) ? (x * cn + xp * sn) : (x * cn - xp * sn))) * sQ);
      x  = O[1][r4][reg];
      xp = __shfl_xor(x, 1);
      Wls[0][row][d] = (__bf16)((((d & 1) ? (x * cn + xp * sn) : (x * cn - xp * sn))) * sK);
      Wls[1][row][d] = (__bf16)O[2][r4][reg];
    }
  __syncthreads();

  __bf16* qdst = Qh + (((size_t)nh * S_LEN + sb + sr) << 6) + sc;
  *(bf16x8*)qdst       = *(bf16x8*)&Xs[sr][sc];
  *(bf16x8*)(qdst + 8) = *(bf16x8*)&Xs[sr][sc + 8];
  __bf16* kdst = Kh + (((size_t)nh * S_LEN + sb + sr) << 6) + sc;
  *(bf16x8*)kdst       = *(bf16x8*)&Wls[0][sr][sc];
  *(bf16x8*)(kdst + 8) = *(bf16x8*)&Wls[0][sr][sc + 8];

  const int dv = tid >> 2, part = tid & 3;
  __bf16 tmp[16];
#pragma unroll
  for (int i = 0; i < 16; ++i) tmp[i] = Wls[1][part * 16 + i][dv];
  __bf16* vdst = Vt + (((size_t)(nh * 64 + dv)) << 11) + sb + part * 16;
  *(bf16x8*)vdst       = *(bf16x8*)&tmp[0];
  *(bf16x8*)(vdst + 8) = *(bf16x8*)&tmp[8];
}

// ---------------------------------------------------------------------------
// Kernel 2: sigmoid-gated attention, split-K chunks.
// R19: R13 body restored exactly (launch_bounds(256,2); R18's (256,4)
// caused VGPR 76->64 + scratch spills, attn 43.4->54.5 — reverted).
// NEW: true-LPT block ordering.  R1's reversal left the SINGLE-chunk
// blocks (t=0..7) last, including rb=7 = 8 tiles (longest chunk class) —
// an end-of-grid straggler.  Remap: bid 0..127 -> singles rb=7..0 FIRST,
// bid 128..1279 -> multis by t descending (ends with rb=8's 4-5-tile
// chunks).  Pure bijection, zero correctness risk.
// Kept from R18: f = 1 - a fold (ONE_EPS==1.0f in fp32; R9-verified).
// ---------------------------------------------------------------------------
__global__ __launch_bounds__(256, 2) void attn_chunk(
    const __bf16* __restrict__ Qh, const __bf16* __restrict__ Kh,
    const __bf16* __restrict__ Vt, const float* __restrict__ imask,
    __bf16* __restrict__ att, float* __restrict__ PartO,
    float* __restrict__ PartP, float* __restrict__ PartA0) {
  const int bid = (int)blockIdx.x;
  int id;
  if (bid < 128) {
    // singles first, largest rb first: rb = 7-(bid>>4), t = rb
    id = ((7 - (bid >> 4)) << 4) + (bid & 15);
  } else {
    // multis: id descends 1279 -> 128 as bid ascends 128 -> 1279
    id = 1407 - bid;
  }
  const int nh = id & 15;
  const int t  = id >> 4;              // 0..79 chunk id within head
  int rb, c, nc;
  if (t < 8)       { rb = t; c = 0; nc = 1; }
  else if (t < 24) { int u = t - 8;  rb = 8  + (u >> 1); c = u & 1;     nc = 2; }
  else if (t < 48) { int u = t - 24; rb = 16 + u / 3;    c = u - 3 * (u / 3); nc = 3; }
  else             { int u = t - 48; rb = 24 + (u >> 2); c = u & 3;     nc = 4; }
  // equal split of T = rb+1 tiles into nc chunks; c=0 is the TOP chunk
  const int T   = rb + 1;
  const int bsz = T / nc;
  const int rem = T - bsz * nc;
  const int szc  = bsz + ((c < rem) ? 1 : 0);
  const int skip = c * bsz + ((c < rem) ? c : rem);
  const int hi = rb - skip;
  const int lo = hi - szc + 1;         // == 0 for c == nc-1

  const int n = nh >> 3, h = nh & 7;
  const int tid = threadIdx.x;
  const int wv = tid >> 6, lane = tid & 63;
  const int l = lane & 15, seg = lane >> 4;
  const int sg4 = seg << 2;
  const int pr = tid >> 3, pc = (tid & 7) << 3;

  __shared__ __bf16 Ks16[64][72];
  __shared__ __bf16 Vt16[64][72];
  __shared__ __bf16 cs16[64][72];      // C^T per wave: rows wv*16+l = q, cols = key
  __shared__ float msk[64];
  __shared__ float v0buf[64];          // V[k0][d] for current tile

  // Q frags: loop-invariant, thread's q = wv*16+l (used as MFMA B operand).
  const __bf16* qbase =
      Qh + (((size_t)nh * S_LEN + rb * 64 + wv * 16 + l) << 6);
  const bf16x8 aq0 = *(const bf16x8*)(qbase + seg * 8);
  const bf16x8 aq1 = *(const bf16x8*)(qbase + seg * 8 + 32);

  f32x4 O[4];                          // O^T: row d = dblk*16+sg4+reg, col q=l
  f32x4 pend[4];
  float Crow = 1.f;
  float a0k0 = 0.f;
#pragma unroll
  for (int d_ = 0; d_ < 4; ++d_) {
    O[d_] = (f32x4){0.f, 0.f, 0.f, 0.f};
    pend[d_] = (f32x4){0.f, 0.f, 0.f, 0.f};
  }

  bf16x8 kp0, kp1, vp0, vp1;
  float mp = 0.f;
#define LOADKV(JT)                                                                     \
  kp0 = *(const bf16x8*)(Kh + (((size_t)nh * S_LEN + (JT) * 64 + pr) << 6) + pc);      \
  kp1 = *(const bf16x8*)(Kh + (((size_t)nh * S_LEN + (JT) * 64 + 32 + pr) << 6) + pc); \
  vp0 = *(const bf16x8*)(Vt + (((size_t)(nh * 64 + pr)) << 11) + (JT) * 64 + pc);      \
  vp1 = *(const bf16x8*)(Vt + (((size_t)(nh * 64 + 32 + pr)) << 11) + (JT) * 64 + pc); \
  if (tid < 64) mp = imask[n * S_LEN + (JT) * 64 + tid];

  LOADKV(hi)

  for (int jt = hi; jt >= lo; --jt) {
    __syncthreads();
    *(bf16x8*)&Ks16[pr][pc]      = kp0;
    *(bf16x8*)&Ks16[32 + pr][pc] = kp1;
    *(bf16x8*)&Vt16[pr][pc]      = vp0;
    *(bf16x8*)&Vt16[32 + pr][pc] = vp1;
    if (tid < 64) msk[tid] = mp;
    if ((tid & 7) == 0) {                      // pc == 0 threads hold k-offset 0
      v0buf[pr]      = (float)vp0[0];
      v0buf[32 + pr] = (float)vp1[0];
    }
    __syncthreads();
    if (jt > lo) { LOADKV(jt - 1) }

    // ---- QK^T (transposed: A=K rows, B=Q) -> S^T[key][q] ----
    f32x4 Sv[4];
    __builtin_amdgcn_s_setprio(1);
#pragma unroll
    for (int nt = 0; nt < 4; ++nt) {
      bf16x8 bk0 = *(const bf16x8*)&Ks16[nt * 16 + l][seg * 8];
      bf16x8 bk1 = *(const bf16x8*)&Ks16[nt * 16 + l][seg * 8 + 32];
      f32x4 z = (f32x4){0.f, 0.f, 0.f, 0.f};
      z = __builtin_amdgcn_mfma_f32_16x16x32_bf16(bk0, aq0, z, 0, 0, 0);
      z = __builtin_amdgcn_mfma_f32_16x16x32_bf16(bk1, aq1, z, 0, 0, 0);
      Sv[nt] = z;
    }
    __builtin_amdgcn_s_setprio(0);

    const bool diag = (jt == rb);        // wave-uniform: only c==0 first tile
    const int qoff = wv * 16 + l;        // local query row of this thread

    // ---- gates ----
    float a_[4][4];
#pragma unroll
    for (int nt = 0; nt < 4; ++nt) {
      const float4 m4 = *(const float4*)&msk[nt * 16 + sg4];
      a_[nt][0] = m4.x * __builtin_amdgcn_rcpf(1.f + __expf(-Sv[nt][0]));
      a_[nt][1] = m4.y * __builtin_amdgcn_rcpf(1.f + __expf(-Sv[nt][1]));
      a_[nt][2] = m4.z * __builtin_amdgcn_rcpf(1.f + __expf(-Sv[nt][2]));
      a_[nt][3] = m4.w * __builtin_amdgcn_rcpf(1.f + __expf(-Sv[nt][3]));
    }
    if (diag) {
#pragma unroll
      for (int nt = 0; nt < 4; ++nt)
#pragma unroll
        for (int reg = 0; reg < 4; ++reg)
          if (nt * 16 + sg4 + reg > qoff) a_[nt][reg] = 0.f;
    }

    // ---- in-register suffix products over keys ----
    float t_[4][4], gp[4], f3s[4];
#pragma unroll
    for (int nt = 0; nt < 4; ++nt) {
      const float f0 = 1.f - a_[nt][0];
      const float f1 = 1.f - a_[nt][1];
      const float f2 = 1.f - a_[nt][2];
      const float f3 = 1.f - a_[nt][3];
      t_[nt][3] = f3;
      t_[nt][2] = f2 * f3;
      t_[nt][1] = f1 * t_[nt][2];
      t_[nt][0] = f0 * t_[nt][1];
      gp[nt] = t_[nt][0];
      f3s[nt] = f3;
    }

    // ---- cross-seg gathers (per 16-key chunk) ----
    float S_[4], GP[4], Xs_[4], Yb[4];
#pragma unroll
    for (int nt = 0; nt < 4; ++nt) {
      const float b = __shfl_xor(gp[nt], 16);   // gp[seg^1]
      const float cc = __shfl_xor(gp[nt], 32);  // gp[seg^2]
      const float dd = __shfl_xor(b, 32);       // gp[seg^3]
      const float cd = cc * dd;
      const float low  = (seg & 1) ? cd : b * cd;   // seg0: bcd, seg1: cd
      const float high = (seg & 1) ? 1.f : b;       // seg2: b,  seg3: 1
      S_[nt] = (seg & 2) ? high : low;          // prod of gp over segs > seg
      GP[nt] = gp[nt] * b * cd;                 // full 16-chunk product
      Xs_[nt] = __shfl_up(f3s[nt], 16);         // f tail of seg-1 (seg>=1)
      Yb[nt] = __shfl(f3s[nt], 48 + l);         // f tail of chunk (seg3), bcast
    }
    const float T2 = GP[3], T1 = T2 * GP[2], T0 = T1 * GP[1];
    const float Tarr[4] = {T0, T1, T2, 1.f};
    const float Ptile = T0 * GP[0];
    const float A0 = __shfl(a_[0][0], l);       // gate of tile key 0, bcast

    // ---- coefficients: cv(key j) = a_j * f_{j-1} * sfx(j) * Crow ----
#pragma unroll
    for (int nt = 0; nt < 4; ++nt) {
      const float wc = S_[nt] * Tarr[nt] * Crow;
      float cv0 = a_[nt][0] * Xs_[nt] * gp[nt] * wc;       // seg>=1 path
      const float cv0s0 = (nt == 0)
          ? ((jt == 0 && nc == 1) ? a_[0][0] : 0.f)        // key 0: direct / pend
          : a_[nt][0] * Yb[nt - 1] * Tarr[nt - 1] * Crow;  // chunk boundary
      if (seg == 0) cv0 = cv0s0;
      const float cv1 = a_[nt][1] * t_[nt][0] * wc;
      const float cv2 = a_[nt][2] * t_[nt][1] * wc;
      const float cv3 = a_[nt][3] * t_[nt][2] * wc;
      bf16x4 pk;
      pk[0] = (__bf16)cv0; pk[1] = (__bf16)cv1;
      pk[2] = (__bf16)cv2; pk[3] = (__bf16)cv3;
      *(bf16x4*)&cs16[wv * 16 + l][nt * 16 + sg4] = pk;
    }

    // ---- pending rank-1 term (key0 of this tile resolves next tile) ----
    const float f63 = Yb[3];
    const float s0 = A0 * Ptile * Crow;
    Crow *= Ptile;
    if (jt == 0) a0k0 = A0;
#pragma unroll
    for (int dblk = 0; dblk < 4; ++dblk) {
      O[dblk][0] += pend[dblk][0] * f63;
      O[dblk][1] += pend[dblk][1] * f63;
      O[dblk][2] += pend[dblk][2] * f63;
      O[dblk][3] += pend[dblk][3] * f63;
      const float4 v4 = *(const float4*)&v0buf[dblk * 16 + sg4];
      pend[dblk][0] = s0 * v4.x; pend[dblk][1] = s0 * v4.y;
      pend[dblk][2] = s0 * v4.z; pend[dblk][3] = s0 * v4.w;
    }

    // ---- PV (transposed: A=V^T rows d, B=C^T) -> O^T ----
    bf16x8 bc0 = *(const bf16x8*)&cs16[wv * 16 + l][seg * 8];
    bf16x8 bc1 = *(const bf16x8*)&cs16[wv * 16 + l][seg * 8 + 32];
    __builtin_amdgcn_s_setprio(1);
#pragma unroll
    for (int dblk = 0; dblk < 4; ++dblk) {
      bf16x8 av0 = *(const bf16x8*)&Vt16[dblk * 16 + l][seg * 8];
      bf16x8 av1 = *(const bf16x8*)&Vt16[dblk * 16 + l][seg * 8 + 32];
      O[dblk] = __builtin_amdgcn_mfma_f32_16x16x32_bf16(av0, bc0, O[dblk], 0, 0, 0);
      O[dblk] = __builtin_amdgcn_mfma_f32_16x16x32_bf16(av1, bc1, O[dblk], 0, 0, 0);
    }
    __builtin_amdgcn_s_setprio(0);
  }

  // ---- low-boundary pending resolution (chunk does not reach key 0) ----
  if (lo > 0) {
    const int m = lo << 6;
    const float mb = imask[n * S_LEN + m - 1];
    const __bf16* kb = Kh + (((size_t)nh * S_LEN + m - 1) << 6) + seg * 16;
    bf16x8 kb0 = *(const bf16x8*)kb, kb1 = *(const bf16x8*)(kb + 8);
    bf16x8 q0 = *(const bf16x8*)(qbase + seg * 16);
    bf16x8 q1 = *(const bf16x8*)(qbase + seg * 16 + 8);
    float sc_ = 0.f;
#pragma unroll
    for (int j = 0; j < 8; ++j)
      sc_ += (float)q0[j] * (float)kb0[j] + (float)q1[j] * (float)kb1[j];
    sc_ += __shfl_xor(sc_, 16);
    sc_ += __shfl_xor(sc_, 32);
    const float fbl = 1.f - mb * __builtin_amdgcn_rcpf(1.f + __expf(-sc_)) + EPS_G;
#pragma unroll
    for (int dblk = 0; dblk < 4; ++dblk) {
      O[dblk][0] += pend[dblk][0] * fbl;
      O[dblk][1] += pend[dblk][1] * fbl;
      O[dblk][2] += pend[dblk][2] * fbl;
      O[dblk][3] += pend[dblk][3] * fbl;
    }
  }

  if (nc == 1) {
    __bf16* arow = att + ((size_t)(n * S_LEN + rb * 64 + wv * 16 + l)) * DMODEL + h * HDIM;
#pragma unroll
    for (int dblk = 0; dblk < 4; ++dblk) {
      bf16x4 ob;
      ob[0] = (__bf16)O[dblk][0]; ob[1] = (__bf16)O[dblk][1];
      ob[2] = (__bf16)O[dblk][2]; ob[3] = (__bf16)O[dblk][3];
      *(bf16x4*)(arow + dblk * 16 + sg4) = ob;
    }
  } else {
    const int slot = nh * 72 + (t - 8);
    float* po = PartO + (size_t)slot * 4096 + (wv * 16 + l) * 64;
#pragma unroll
    for (int dblk = 0; dblk < 4; ++dblk) {
      float4 v;
      v.x = O[dblk][0]; v.y = O[dblk][1]; v.z = O[dblk][2]; v.w = O[dblk][3];
      *(float4*)(po + dblk * 16 + sg4) = v;
    }
    if (seg == 0) {
      PartP[slot * 64 + wv * 16 + l] = Crow;
      if (lo == 0)
        PartA0[(nh * 24 + rb - 8) * 64 + wv * 16 + l] = a0k0;
    }
  }
}

// ---------------------------------------------------------------------------
// Kernel 3: combine chunk partials: O = sum_c (prod_{c'<c} P_c') O_c + a0 (x) V0
// ---------------------------------------------------------------------------
__global__ __launch_bounds__(256) void combine_kernel(
    const float* __restrict__ PartO, const float* __restrict__ PartP,
    const float* __restrict__ PartA0, const __bf16* __restrict__ Vt,
    __bf16* __restrict__ att) {
  const int b = blockIdx.x;            // 16 x 24
  const int nh = b / 24;
  const int rb = 8 + (b - nh * 24);
  const int nc = (rb < 16) ? 2 : ((rb < 24) ? 3 : 4);
  const int t0 = (rb < 16) ? 8 + ((rb - 8) << 1)
               : (rb < 24) ? 24 + (rb - 16) * 3
                           : 48 + ((rb - 24) << 2);
  const int n = nh >> 3, h = nh & 7;
  const int tid = threadIdx.x;
  const int r = tid >> 2, db = (tid & 3) << 4;

  float acc[16];
#pragma unroll
  for (int j = 0; j < 16; ++j) acc[j] = 0.f;
  float fac = 1.f;
  for (int c = 0; c < nc; ++c) {
    const int slot = nh * 72 + (t0 - 8) + c;
    const float* po = PartO + (size_t)slot * 4096 + r * 64 + db;
    const float P = PartP[slot * 64 + r];
#pragma unroll
    for (int q = 0; q < 4; ++q) {
      const float4 v = *(const float4*)(po + q * 4);
      acc[q * 4 + 0] += fac * v.x; acc[q * 4 + 1] += fac * v.y;
      acc[q * 4 + 2] += fac * v.z; acc[q * 4 + 3] += fac * v.w;
    }
    fac *= P;
  }
  const float a0 = PartA0[(nh * 24 + rb - 8) * 64 + r];
#pragma unroll
  for (int j = 0; j < 16; ++j)
    acc[j] += a0 * (float)Vt[(((size_t)(nh * 64 + db + j)) << 11)];

  __bf16 ob[16];
#pragma unroll
  for (int j = 0; j < 16; ++j) ob[j] = (__bf16)acc[j];
  __bf16* dst = att + ((size_t)(n * S_LEN + rb * 64 + r)) * DMODEL + h * HDIM + db;
  *(bf16x8*)dst       = *(bf16x8*)&ob[0];
  *(bf16x8*)(dst + 8) = *(bf16x8*)&ob[8];
}

// ---------------------------------------------------------------------------
// Kernel 4: out = att @ Wo^T + bo.  R10 wave decomposition: wave owns all
// 64 rows (4 A-frags) x units {wv, wv+4}: 16 MFMAs / 12 LDS reads per k-iter.
// ---------------------------------------------------------------------------
__global__ __launch_bounds__(256, 2) void out_gemm(const __bf16* __restrict__ Xa,
                                                   const __bf16* __restrict__ Wob,
                                                   const float* __restrict__ bo,
                                                   float* __restrict__ Out) {
  const int i0 = blockIdx.x << 6, j0 = blockIdx.y << 7;
  __shared__ __bf16 As[64][72];
  __shared__ __bf16 Bs[128][72];

  const int tid = threadIdx.x;
  const int wv = tid >> 6, lane = tid & 63;
  const int l = lane & 15, seg = lane >> 4;
  const int sr = tid >> 2, sc = (tid & 3) << 4;

  f32x4 O[2][4];                       // [j][r4]; unit u = wv + 4*j
#pragma unroll
  for (int j = 0; j < 2; ++j)
#pragma unroll
    for (int r4 = 0; r4 < 4; ++r4) O[j][r4] = (f32x4){0.f, 0.f, 0.f, 0.f};

  bf16x8 ar0, ar1, br[2][2];
#define LOADOUT(K0)                                                          \
  {                                                                          \
    const __bf16* xp = Xa + (size_t)(i0 + sr) * 512 + (K0) + sc;             \
    ar0 = *(const bf16x8*)xp; ar1 = *(const bf16x8*)(xp + 8);                \
    _Pragma("unroll")                                                        \
    for (int ps = 0; ps < 2; ++ps) {                                         \
      const __bf16* wp = Wob + (size_t)(j0 + ps * 64 + sr) * 512 + (K0) + sc;\
      br[ps][0] = *(const bf16x8*)wp; br[ps][1] = *(const bf16x8*)(wp + 8);  \
    }                                                                        \
  }

  LOADOUT(0)
  for (int k0 = 0; k0 < 512; k0 += 64) {
    __syncthreads();
    *(bf16x8*)&As[sr][sc]     = ar0;
    *(bf16x8*)&As[sr][sc + 8] = ar1;
#pragma unroll
    for (int ps = 0; ps < 2; ++ps) {
      *(bf16x8*)&Bs[ps * 64 + sr][sc]     = br[ps][0];
      *(bf16x8*)&Bs[ps * 64 + sr][sc + 8] = br[ps][1];
    }
    __syncthreads();
    if (k0 < 448) LOADOUT(k0 + 64)

    bf16x8 a0[4], a1[4];
#pragma unroll
    for (int r4 = 0; r4 < 4; ++r4) {
      a0[r4] = *(const bf16x8*)&As[r4 * 16 + l][seg * 8];
      a1[r4] = *(const bf16x8*)&As[r4 * 16 + l][seg * 8 + 32];
    }
#pragma unroll
    for (int j = 0; j < 2; ++j) {
      const int u = wv + 4 * j;
      bf16x8 b0 = *(const bf16x8*)&Bs[u * 16 + l][seg * 8];
      bf16x8 b1 = *(const bf16x8*)&Bs[u * 16 + l][seg * 8 + 32];
#pragma unroll
      for (int r4 = 0; r4 < 4; ++r4) {
        O[j][r4] = __builtin_amdgcn_mfma_f32_16x16x32_bf16(a0[r4], b0, O[j][r4], 0, 0, 0);
        O[j][r4] = __builtin_amdgcn_mfma_f32_16x16x32_bf16(a1[r4], b1, O[j][r4], 0, 0, 0);
      }
    }
  }

#pragma unroll
  for (int j = 0; j < 2; ++j) {
    const int u = wv + 4 * j;
    const float bb = bo[j0 + u * 16 + l];
#pragma unroll
    for (int r4 = 0; r4 < 4; ++r4)
#pragma unroll
      for (int reg = 0; reg < 4; ++reg) {
        const int m = r4 * 16 + (seg << 2) + reg;
        Out[(size_t)(i0 + m) * 512 + j0 + u * 16 + l] = O[j][r4][reg] + bb;
      }
  }
}

// ---------------------------------------------------------------------------
extern "C" void kernel_launch(void* const* d_in, const int* in_sizes, int n_in,
                              void* d_out, int out_size, void* d_ws, size_t ws_size,
                              hipStream_t stream) {
  (void)in_sizes; (void)n_in; (void)out_size; (void)ws_size;
  const float* seq  = (const float*)d_in[0];
  const float* mask = (const float*)d_in[1];
  const int*   pos  = (const int*)d_in[2];
  const float* Wq = (const float*)d_in[4];
  const float* bq = (const float*)d_in[5];
  const float* Wk = (const float*)d_in[6];
  const float* bk = (const float*)d_in[7];
  const float* Wv = (const float*)d_in[8];
  const float* bv = (const float*)d_in[9];
  const float* Wo = (const float*)d_in[10];
  const float* bo = (const float*)d_in[11];
  float* out = (float*)d_out;

  char* base = (char*)d_ws;
  __bf16* att = (__bf16*)base;                     // 4 MB  (4096 x 512 bf16)
  __bf16* Qh  = (__bf16*)(base + ( 4u << 20));     // 4 MB
  __bf16* Kh  = (__bf16*)(base + ( 8u << 20));     // 4 MB
  __bf16* Vt  = (__bf16*)(base + (12u << 20));     // 4 MB  [nh][d][2048]
  __bf16* Wb  = (__bf16*)(base + (16u << 20));     // 1.5 MB
  __bf16* Wob = (__bf16*)(base + (18u << 20));     // 0.5 MB
  __bf16* Xb  = (__bf16*)(base + (19u << 20));     // 4 MB  (dead after qkv)
  float* PartO  = (float*)(base + (23u << 20));    // 16*72*4096*4 = 18.9 MB
  float* PartP  = (float*)(base + (42u << 20));    // 16*72*64*4   = 295 KB
  float* PartA0 = (float*)(base + (43u << 20));    // 16*24*64*4   = 98 KB

  cvt_kernel<<<3072, 256, 0, stream>>>(seq, Wq, Wk, Wv, Wo, Xb, Wb, Wob);
  qkv_gemm<<<dim3(64, 8), 256, 0, stream>>>(Xb, Wb, bq, bk, bv, pos, Qh, Kh, Vt);
  attn_chunk<<<1280, 256, 0, stream>>>(Qh, Kh, Vt, mask, att, PartO, PartP, PartA0);
  combine_kernel<<<384, 256, 0, stream>>>(PartO, PartP, PartA0, Vt, att);
  out_gemm<<<dim3(64, 4), 256, 0, stream>>>(att, Wob, bo, out);
}

// Round 11
// 145.202 us; speedup vs baseline: 1.1265x; 1.0207x over previous
//
#include <hip/hip_runtime.h>
#include <math.h>

#define S_LEN 2048
#define DMODEL 512
#define HDIM 64
#define EPS_G 1e-8f

typedef __bf16 bf16x8 __attribute__((ext_vector_type(8)));
typedef __bf16 bf16x4 __attribute__((ext_vector_type(4)));
typedef float f32x4 __attribute__((ext_vector_type(4)));

// ---------------------------------------------------------------------------
// Kernel 0: one-shot f32->bf16 conversion of the WEIGHTS only (R20: X
// conversion fused into qkv_gemm — X was 67% of this kernel's traffic).
// ---------------------------------------------------------------------------
__global__ __launch_bounds__(256) void cvt_kernel(
    const float* __restrict__ Wq, const float* __restrict__ Wk,
    const float* __restrict__ Wv, const float* __restrict__ Wo,
    __bf16* __restrict__ Wb, __bf16* __restrict__ Wob) {
  const int u = blockIdx.x * 256 + threadIdx.x;   // float4 unit, 262144 total
  const float* src; __bf16* dst; int off;
  if (u < 65536)       { src = Wq; dst = Wb;          off = u; }
  else if (u < 131072) { src = Wk; dst = Wb + 262144; off = u - 65536; }
  else if (u < 196608) { src = Wv; dst = Wb + 524288; off = u - 131072; }
  else                 { src = Wo; dst = Wob;         off = u - 196608; }
  const float4 v = *(const float4*)(src + (size_t)off * 4);
  bf16x4 o;
  o[0] = (__bf16)v.x; o[1] = (__bf16)v.y; o[2] = (__bf16)v.z; o[3] = (__bf16)v.w;
  *(bf16x4*)(dst + (size_t)off * 4) = o;
}

// ---------------------------------------------------------------------------
// Kernel 1: fused QKV projection.  R20: X read directly from seq (f32) and
// converted in-register during staging — same (__bf16) cast as the old cvt,
// bit-identical numerics.  Weights remain pre-converted bf16 (read 64x each,
// f32 would add 96 MB of L3 traffic).
// ---------------------------------------------------------------------------
__global__ __launch_bounds__(256, 2) void qkv_gemm(
    const float* __restrict__ Xf, const __bf16* __restrict__ Wb,
    const float* __restrict__ bq, const float* __restrict__ bk, const float* __restrict__ bv,
    const int* __restrict__ pos,
    __bf16* __restrict__ Qh, __bf16* __restrict__ Kh, __bf16* __restrict__ Vt) {
  const int i0 = blockIdx.x << 6;
  const int h  = blockIdx.y;           // 0..7
  const int j0 = h << 6;

  __shared__ __bf16 Xs[64][72];
  __shared__ __bf16 Wls[3][64][72];

  const int tid = threadIdx.x;
  const int wv = tid >> 6, lane = tid & 63;
  const int l = lane & 15, seg = lane >> 4;
  const int sr = tid >> 2, sc = (tid & 3) << 4;

  f32x4 O[3][4];                       // [w][r4], rows r4*16+seg*4+reg, col wv*16+l
#pragma unroll
  for (int w = 0; w < 3; ++w)
#pragma unroll
    for (int r4 = 0; r4 < 4; ++r4) O[w][r4] = (f32x4){0.f, 0.f, 0.f, 0.f};

  bf16x8 xr0, xr1, wr[3][2];
#define LOADQKV(K0)                                                                   \
  {                                                                                   \
    const float* xp = Xf + (size_t)(i0 + sr) * 512 + (K0) + sc;                       \
    const float4 f0 = *(const float4*)xp;                                             \
    const float4 f1 = *(const float4*)(xp + 4);                                       \
    const float4 f2 = *(const float4*)(xp + 8);                                       \
    const float4 f3 = *(const float4*)(xp + 12);                                      \
    xr0[0] = (__bf16)f0.x; xr0[1] = (__bf16)f0.y; xr0[2] = (__bf16)f0.z;              \
    xr0[3] = (__bf16)f0.w; xr0[4] = (__bf16)f1.x; xr0[5] = (__bf16)f1.y;              \
    xr0[6] = (__bf16)f1.z; xr0[7] = (__bf16)f1.w;                                     \
    xr1[0] = (__bf16)f2.x; xr1[1] = (__bf16)f2.y; xr1[2] = (__bf16)f2.z;              \
    xr1[3] = (__bf16)f2.w; xr1[4] = (__bf16)f3.x; xr1[5] = (__bf16)f3.y;              \
    xr1[6] = (__bf16)f3.z; xr1[7] = (__bf16)f3.w;                                     \
    _Pragma("unroll")                                                                 \
    for (int w = 0; w < 3; ++w) {                                                     \
      const __bf16* wp = Wb + (size_t)w * 262144 + (size_t)(j0 + sr) * 512 + (K0) + sc;\
      wr[w][0] = *(const bf16x8*)wp; wr[w][1] = *(const bf16x8*)(wp + 8);             \
    }                                                                                 \
  }

  LOADQKV(0)
  for (int k0 = 0; k0 < 512; k0 += 64) {
    __syncthreads();
    *(bf16x8*)&Xs[sr][sc]     = xr0;
    *(bf16x8*)&Xs[sr][sc + 8] = xr1;
#pragma unroll
    for (int w = 0; w < 3; ++w) {
      *(bf16x8*)&Wls[w][sr][sc]     = wr[w][0];
      *(bf16x8*)&Wls[w][sr][sc + 8] = wr[w][1];
    }
    __syncthreads();
    if (k0 < 448) LOADQKV(k0 + 64)

    bf16x8 a0[4], a1[4];
#pragma unroll
    for (int r4 = 0; r4 < 4; ++r4) {
      a0[r4] = *(const bf16x8*)&Xs[r4 * 16 + l][seg * 8];
      a1[r4] = *(const bf16x8*)&Xs[r4 * 16 + l][seg * 8 + 32];
    }
#pragma unroll
    for (int w = 0; w < 3; ++w) {
      bf16x8 b0 = *(const bf16x8*)&Wls[w][wv * 16 + l][seg * 8];
      bf16x8 b1 = *(const bf16x8*)&Wls[w][wv * 16 + l][seg * 8 + 32];
#pragma unroll
      for (int r4 = 0; r4 < 4; ++r4) {
        O[w][r4] = __builtin_amdgcn_mfma_f32_16x16x32_bf16(a0[r4], b0, O[w][r4], 0, 0, 0);
        O[w][r4] = __builtin_amdgcn_mfma_f32_16x16x32_bf16(a1[r4], b1, O[w][r4], 0, 0, 0);
      }
    }
  }

  // bias (col d = wv*16+l fixed per thread)
  const int d = wv * 16 + l;
  const float bbq = bq[j0 + d], bbk = bk[j0 + d], bbv = bv[j0 + d];
#pragma unroll
  for (int r4 = 0; r4 < 4; ++r4)
#pragma unroll
    for (int reg = 0; reg < 4; ++reg) {
      O[0][r4][reg] += bbq; O[1][r4][reg] += bbk; O[2][r4][reg] += bbv;
    }

  const int n = i0 >> 11, sb = i0 & 2047;
  const int nh = (n << 3) + h;

  // xpos constants: single (kp) per thread since nt==wv
  const float kp   = (float)(d >> 1);
  const float invf = exp2f(-0.41524100f * kp) * 0.15915494f;  // rev / unit pos
  const float l2sv = log2f((2.f * kp + 25.6f) * (1.f / 89.6f));
  float pv_[4][4];
#pragma unroll
  for (int r4 = 0; r4 < 4; ++r4)
#pragma unroll
    for (int reg = 0; reg < 4; ++reg)
      pv_[r4][reg] = (float)pos[n * S_LEN + sb + r4 * 16 + (seg << 2) + reg];

  __syncthreads();   // last MFMA reads done; Xs/Wls become epilogue bounces

#pragma unroll
  for (int r4 = 0; r4 < 4; ++r4)
#pragma unroll
    for (int reg = 0; reg < 4; ++reg) {
      const int row = r4 * 16 + (seg << 2) + reg;
      const float p = pv_[r4][reg];
      const float rev0 = p * invf;
      const float rev  = rev0 - floorf(rev0);
      const float sn = __builtin_amdgcn_sinf(rev);
      const float cn = __builtin_amdgcn_cosf(rev);
      const float sq = exp2f(p * (1.f / 512.f) * l2sv);
      const float sQ = sq * 0.125f;                   // fused HEAD_DIM^-0.5
      const float sK = __builtin_amdgcn_rcpf(sq);     // downscale for K
      float x  = O[0][r4][reg];
      float xp = __shfl_xor(x, 1);
      Xs[row][d] = (__bf16)((((d & 1) ? (x * cn + xp * sn) : (x * cn - xp * sn))) * sQ);
      x  = O[1][r4][reg];
      xp = __shfl_xor(x, 1);
      Wls[0][row][d] = (__bf16)((((d & 1) ? (x * cn + xp * sn) : (x * cn - xp * sn))) * sK);
      Wls[1][row][d] = (__bf16)O[2][r4][reg];
    }
  __syncthreads();

  __bf16* qdst = Qh + (((size_t)nh * S_LEN + sb + sr) << 6) + sc;
  *(bf16x8*)qdst       = *(bf16x8*)&Xs[sr][sc];
  *(bf16x8*)(qdst + 8) = *(bf16x8*)&Xs[sr][sc + 8];
  __bf16* kdst = Kh + (((size_t)nh * S_LEN + sb + sr) << 6) + sc;
  *(bf16x8*)kdst       = *(bf16x8*)&Wls[0][sr][sc];
  *(bf16x8*)(kdst + 8) = *(bf16x8*)&Wls[0][sr][sc + 8];

  const int dv = tid >> 2, part = tid & 3;
  __bf16 tmp[16];
#pragma unroll
  for (int i = 0; i < 16; ++i) tmp[i] = Wls[1][part * 16 + i][dv];
  __bf16* vdst = Vt + (((size_t)(nh * 64 + dv)) << 11) + sb + part * 16;
  *(bf16x8*)vdst       = *(bf16x8*)&tmp[0];
  *(bf16x8*)(vdst + 8) = *(bf16x8*)&tmp[8];
}

// ---------------------------------------------------------------------------
// Kernel 2: sigmoid-gated attention, split-K chunks.  R13 body (proven).
// R20 ordering: PERFECT LPT tail — big singles (rb 7..4) first, multis
// t=79..8 descending (sizes 8 -> 4), SMALL singles (rb 3..0: 4,3,2,1 tiles)
// LAST so the grid drains on the shortest chunks.  Pure bijection.
// ---------------------------------------------------------------------------
__global__ __launch_bounds__(256, 2) void attn_chunk(
    const __bf16* __restrict__ Qh, const __bf16* __restrict__ Kh,
    const __bf16* __restrict__ Vt, const float* __restrict__ imask,
    __bf16* __restrict__ att, float* __restrict__ PartO,
    float* __restrict__ PartP, float* __restrict__ PartA0) {
  const int bid = (int)blockIdx.x;
  int id;
  if (bid < 64) {
    id = ((7 - (bid >> 4)) << 4) + (bid & 15);          // singles rb=7..4
  } else if (bid < 1216) {
    id = 1343 - bid;                                    // multis t=79..8
  } else {
    id = ((3 - ((bid - 1216) >> 4)) << 4) + (bid & 15); // singles rb=3..0
  }
  const int nh = id & 15;
  const int t  = id >> 4;              // 0..79 chunk id within head
  int rb, c, nc;
  if (t < 8)       { rb = t; c = 0; nc = 1; }
  else if (t < 24) { int u = t - 8;  rb = 8  + (u >> 1); c = u & 1;     nc = 2; }
  else if (t < 48) { int u = t - 24; rb = 16 + u / 3;    c = u - 3 * (u / 3); nc = 3; }
  else             { int u = t - 48; rb = 24 + (u >> 2); c = u & 3;     nc = 4; }
  // equal split of T = rb+1 tiles into nc chunks; c=0 is the TOP chunk
  const int T   = rb + 1;
  const int bsz = T / nc;
  const int rem = T - bsz * nc;
  const int szc  = bsz + ((c < rem) ? 1 : 0);
  const int skip = c * bsz + ((c < rem) ? c : rem);
  const int hi = rb - skip;
  const int lo = hi - szc + 1;         // == 0 for c == nc-1

  const int n = nh >> 3, h = nh & 7;
  const int tid = threadIdx.x;
  const int wv = tid >> 6, lane = tid & 63;
  const int l = lane & 15, seg = lane >> 4;
  const int sg4 = seg << 2;
  const int pr = tid >> 3, pc = (tid & 7) << 3;

  __shared__ __bf16 Ks16[64][72];
  __shared__ __bf16 Vt16[64][72];
  __shared__ __bf16 cs16[64][72];      // C^T per wave: rows wv*16+l = q, cols = key
  __shared__ float msk[64];
  __shared__ float v0buf[64];          // V[k0][d] for current tile

  // Q frags: loop-invariant, thread's q = wv*16+l (used as MFMA B operand).
  const __bf16* qbase =
      Qh + (((size_t)nh * S_LEN + rb * 64 + wv * 16 + l) << 6);
  const bf16x8 aq0 = *(const bf16x8*)(qbase + seg * 8);
  const bf16x8 aq1 = *(const bf16x8*)(qbase + seg * 8 + 32);

  f32x4 O[4];                          // O^T: row d = dblk*16+sg4+reg, col q=l
  f32x4 pend[4];
  float Crow = 1.f;
  float a0k0 = 0.f;
#pragma unroll
  for (int d_ = 0; d_ < 4; ++d_) {
    O[d_] = (f32x4){0.f, 0.f, 0.f, 0.f};
    pend[d_] = (f32x4){0.f, 0.f, 0.f, 0.f};
  }

  bf16x8 kp0, kp1, vp0, vp1;
  float mp = 0.f;
#define LOADKV(JT)                                                                     \
  kp0 = *(const bf16x8*)(Kh + (((size_t)nh * S_LEN + (JT) * 64 + pr) << 6) + pc);      \
  kp1 = *(const bf16x8*)(Kh + (((size_t)nh * S_LEN + (JT) * 64 + 32 + pr) << 6) + pc); \
  vp0 = *(const bf16x8*)(Vt + (((size_t)(nh * 64 + pr)) << 11) + (JT) * 64 + pc);      \
  vp1 = *(const bf16x8*)(Vt + (((size_t)(nh * 64 + 32 + pr)) << 11) + (JT) * 64 + pc); \
  if (tid < 64) mp = imask[n * S_LEN + (JT) * 64 + tid];

  LOADKV(hi)

  for (int jt = hi; jt >= lo; --jt) {
    __syncthreads();
    *(bf16x8*)&Ks16[pr][pc]      = kp0;
    *(bf16x8*)&Ks16[32 + pr][pc] = kp1;
    *(bf16x8*)&Vt16[pr][pc]      = vp0;
    *(bf16x8*)&Vt16[32 + pr][pc] = vp1;
    if (tid < 64) msk[tid] = mp;
    if ((tid & 7) == 0) {                      // pc == 0 threads hold k-offset 0
      v0buf[pr]      = (float)vp0[0];
      v0buf[32 + pr] = (float)vp1[0];
    }
    __syncthreads();
    if (jt > lo) { LOADKV(jt - 1) }

    // ---- QK^T (transposed: A=K rows, B=Q) -> S^T[key][q] ----
    f32x4 Sv[4];
    __builtin_amdgcn_s_setprio(1);
#pragma unroll
    for (int nt = 0; nt < 4; ++nt) {
      bf16x8 bk0 = *(const bf16x8*)&Ks16[nt * 16 + l][seg * 8];
      bf16x8 bk1 = *(const bf16x8*)&Ks16[nt * 16 + l][seg * 8 + 32];
      f32x4 z = (f32x4){0.f, 0.f, 0.f, 0.f};
      z = __builtin_amdgcn_mfma_f32_16x16x32_bf16(bk0, aq0, z, 0, 0, 0);
      z = __builtin_amdgcn_mfma_f32_16x16x32_bf16(bk1, aq1, z, 0, 0, 0);
      Sv[nt] = z;
    }
    __builtin_amdgcn_s_setprio(0);

    const bool diag = (jt == rb);        // wave-uniform: only c==0 first tile
    const int qoff = wv * 16 + l;        // local query row of this thread

    // ---- gates ----
    float a_[4][4];
#pragma unroll
    for (int nt = 0; nt < 4; ++nt) {
      const float4 m4 = *(const float4*)&msk[nt * 16 + sg4];
      a_[nt][0] = m4.x * __builtin_amdgcn_rcpf(1.f + __expf(-Sv[nt][0]));
      a_[nt][1] = m4.y * __builtin_amdgcn_rcpf(1.f + __expf(-Sv[nt][1]));
      a_[nt][2] = m4.z * __builtin_amdgcn_rcpf(1.f + __expf(-Sv[nt][2]));
      a_[nt][3] = m4.w * __builtin_amdgcn_rcpf(1.f + __expf(-Sv[nt][3]));
    }
    if (diag) {
#pragma unroll
      for (int nt = 0; nt < 4; ++nt)
#pragma unroll
        for (int reg = 0; reg < 4; ++reg)
          if (nt * 16 + sg4 + reg > qoff) a_[nt][reg] = 0.f;
    }

    // ---- in-register suffix products over keys ----
    float t_[4][4], gp[4], f3s[4];
#pragma unroll
    for (int nt = 0; nt < 4; ++nt) {
      const float f0 = 1.f - a_[nt][0];
      const float f1 = 1.f - a_[nt][1];
      const float f2 = 1.f - a_[nt][2];
      const float f3 = 1.f - a_[nt][3];
      t_[nt][3] = f3;
      t_[nt][2] = f2 * f3;
      t_[nt][1] = f1 * t_[nt][2];
      t_[nt][0] = f0 * t_[nt][1];
      gp[nt] = t_[nt][0];
      f3s[nt] = f3;
    }

    // ---- cross-seg gathers (per 16-key chunk) ----
    float S_[4], GP[4], Xs_[4], Yb[4];
#pragma unroll
    for (int nt = 0; nt < 4; ++nt) {
      const float b = __shfl_xor(gp[nt], 16);   // gp[seg^1]
      const float cc = __shfl_xor(gp[nt], 32);  // gp[seg^2]
      const float dd = __shfl_xor(b, 32);       // gp[seg^3]
      const float cd = cc * dd;
      const float low  = (seg & 1) ? cd : b * cd;   // seg0: bcd, seg1: cd
      const float high = (seg & 1) ? 1.f : b;       // seg2: b,  seg3: 1
      S_[nt] = (seg & 2) ? high : low;          // prod of gp over segs > seg
      GP[nt] = gp[nt] * b * cd;                 // full 16-chunk product
      Xs_[nt] = __shfl_up(f3s[nt], 16);         // f tail of seg-1 (seg>=1)
      Yb[nt] = __shfl(f3s[nt], 48 + l);         // f tail of chunk (seg3), bcast
    }
    const float T2 = GP[3], T1 = T2 * GP[2], T0 = T1 * GP[1];
    const float Tarr[4] = {T0, T1, T2, 1.f};
    const float Ptile = T0 * GP[0];
    const float A0 = __shfl(a_[0][0], l);       // gate of tile key 0, bcast

    // ---- coefficients: cv(key j) = a_j * f_{j-1} * sfx(j) * Crow ----
#pragma unroll
    for (int nt = 0; nt < 4; ++nt) {
      const float wc = S_[nt] * Tarr[nt] * Crow;
      float cv0 = a_[nt][0] * Xs_[nt] * gp[nt] * wc;       // seg>=1 path
      const float cv0s0 = (nt == 0)
          ? ((jt == 0 && nc == 1) ? a_[0][0] : 0.f)        // key 0: direct / pend
          : a_[nt][0] * Yb[nt - 1] * Tarr[nt - 1] * Crow;  // chunk boundary
      if (seg == 0) cv0 = cv0s0;
      const float cv1 = a_[nt][1] * t_[nt][0] * wc;
      const float cv2 = a_[nt][2] * t_[nt][1] * wc;
      const float cv3 = a_[nt][3] * t_[nt][2] * wc;
      bf16x4 pk;
      pk[0] = (__bf16)cv0; pk[1] = (__bf16)cv1;
      pk[2] = (__bf16)cv2; pk[3] = (__bf16)cv3;
      *(bf16x4*)&cs16[wv * 16 + l][nt * 16 + sg4] = pk;
    }

    // ---- pending rank-1 term (key0 of this tile resolves next tile) ----
    const float f63 = Yb[3];
    const float s0 = A0 * Ptile * Crow;
    Crow *= Ptile;
    if (jt == 0) a0k0 = A0;
#pragma unroll
    for (int dblk = 0; dblk < 4; ++dblk) {
      O[dblk][0] += pend[dblk][0] * f63;
      O[dblk][1] += pend[dblk][1] * f63;
      O[dblk][2] += pend[dblk][2] * f63;
      O[dblk][3] += pend[dblk][3] * f63;
      const float4 v4 = *(const float4*)&v0buf[dblk * 16 + sg4];
      pend[dblk][0] = s0 * v4.x; pend[dblk][1] = s0 * v4.y;
      pend[dblk][2] = s0 * v4.z; pend[dblk][3] = s0 * v4.w;
    }

    // ---- PV (transposed: A=V^T rows d, B=C^T) -> O^T ----
    bf16x8 bc0 = *(const bf16x8*)&cs16[wv * 16 + l][seg * 8];
    bf16x8 bc1 = *(const bf16x8*)&cs16[wv * 16 + l][seg * 8 + 32];
    __builtin_amdgcn_s_setprio(1);
#pragma unroll
    for (int dblk = 0; dblk < 4; ++dblk) {
      bf16x8 av0 = *(const bf16x8*)&Vt16[dblk * 16 + l][seg * 8];
      bf16x8 av1 = *(const bf16x8*)&Vt16[dblk * 16 + l][seg * 8 + 32];
      O[dblk] = __builtin_amdgcn_mfma_f32_16x16x32_bf16(av0, bc0, O[dblk], 0, 0, 0);
      O[dblk] = __builtin_amdgcn_mfma_f32_16x16x32_bf16(av1, bc1, O[dblk], 0, 0, 0);
    }
    __builtin_amdgcn_s_setprio(0);
  }

  // ---- low-boundary pending resolution (chunk does not reach key 0) ----
  if (lo > 0) {
    const int m = lo << 6;
    const float mb = imask[n * S_LEN + m - 1];
    const __bf16* kb = Kh + (((size_t)nh * S_LEN + m - 1) << 6) + seg * 16;
    bf16x8 kb0 = *(const bf16x8*)kb, kb1 = *(const bf16x8*)(kb + 8);
    bf16x8 q0 = *(const bf16x8*)(qbase + seg * 16);
    bf16x8 q1 = *(const bf16x8*)(qbase + seg * 16 + 8);
    float sc_ = 0.f;
#pragma unroll
    for (int j = 0; j < 8; ++j)
      sc_ += (float)q0[j] * (float)kb0[j] + (float)q1[j] * (float)kb1[j];
    sc_ += __shfl_xor(sc_, 16);
    sc_ += __shfl_xor(sc_, 32);
    const float fbl = 1.f - mb * __builtin_amdgcn_rcpf(1.f + __expf(-sc_)) + EPS_G;
#pragma unroll
    for (int dblk = 0; dblk < 4; ++dblk) {
      O[dblk][0] += pend[dblk][0] * fbl;
      O[dblk][1] += pend[dblk][1] * fbl;
      O[dblk][2] += pend[dblk][2] * fbl;
      O[dblk][3] += pend[dblk][3] * fbl;
    }
  }

  if (nc == 1) {
    __bf16* arow = att + ((size_t)(n * S_LEN + rb * 64 + wv * 16 + l)) * DMODEL + h * HDIM;
#pragma unroll
    for (int dblk = 0; dblk < 4; ++dblk) {
      bf16x4 ob;
      ob[0] = (__bf16)O[dblk][0]; ob[1] = (__bf16)O[dblk][1];
      ob[2] = (__bf16)O[dblk][2]; ob[3] = (__bf16)O[dblk][3];
      *(bf16x4*)(arow + dblk * 16 + sg4) = ob;
    }
  } else {
    const int slot = nh * 72 + (t - 8);
    float* po = PartO + (size_t)slot * 4096 + (wv * 16 + l) * 64;
#pragma unroll
    for (int dblk = 0; dblk < 4; ++dblk) {
      float4 v;
      v.x = O[dblk][0]; v.y = O[dblk][1]; v.z = O[dblk][2]; v.w = O[dblk][3];
      *(float4*)(po + dblk * 16 + sg4) = v;
    }
    if (seg == 0) {
      PartP[slot * 64 + wv * 16 + l] = Crow;
      if (lo == 0)
        PartA0[(nh * 24 + rb - 8) * 64 + wv * 16 + l] = a0k0;
    }
  }
}

// ---------------------------------------------------------------------------
// Kernel 3: combine chunk partials: O = sum_c (prod_{c'<c} P_c') O_c + a0 (x) V0
// ---------------------------------------------------------------------------
__global__ __launch_bounds__(256) void combine_kernel(
    const float* __restrict__ PartO, const float* __restrict__ PartP,
    const float* __restrict__ PartA0, const __bf16* __restrict__ Vt,
    __bf16* __restrict__ att) {
  const int b = blockIdx.x;            // 16 x 24
  const int nh = b / 24;
  const int rb = 8 + (b - nh * 24);
  const int nc = (rb < 16) ? 2 : ((rb < 24) ? 3 : 4);
  const int t0 = (rb < 16) ? 8 + ((rb - 8) << 1)
               : (rb < 24) ? 24 + (rb - 16) * 3
                           : 48 + ((rb - 24) << 2);
  const int n = nh >> 3, h = nh & 7;
  const int tid = threadIdx.x;
  const int r = tid >> 2, db = (tid & 3) << 4;

  float acc[16];
#pragma unroll
  for (int j = 0; j < 16; ++j) acc[j] = 0.f;
  float fac = 1.f;
  for (int c = 0; c < nc; ++c) {
    const int slot = nh * 72 + (t0 - 8) + c;
    const float* po = PartO + (size_t)slot * 4096 + r * 64 + db;
    const float P = PartP[slot * 64 + r];
#pragma unroll
    for (int q = 0; q < 4; ++q) {
      const float4 v = *(const float4*)(po + q * 4);
      acc[q * 4 + 0] += fac * v.x; acc[q * 4 + 1] += fac * v.y;
      acc[q * 4 + 2] += fac * v.z; acc[q * 4 + 3] += fac * v.w;
    }
    fac *= P;
  }
  const float a0 = PartA0[(nh * 24 + rb - 8) * 64 + r];
#pragma unroll
  for (int j = 0; j < 16; ++j)
    acc[j] += a0 * (float)Vt[(((size_t)(nh * 64 + db + j)) << 11)];

  __bf16 ob[16];
#pragma unroll
  for (int j = 0; j < 16; ++j) ob[j] = (__bf16)acc[j];
  __bf16* dst = att + ((size_t)(n * S_LEN + rb * 64 + r)) * DMODEL + h * HDIM + db;
  *(bf16x8*)dst       = *(bf16x8*)&ob[0];
  *(bf16x8*)(dst + 8) = *(bf16x8*)&ob[8];
}

// ---------------------------------------------------------------------------
// Kernel 4: out = att @ Wo^T + bo.  R10 wave decomposition: wave owns all
// 64 rows (4 A-frags) x units {wv, wv+4}: 16 MFMAs / 12 LDS reads per k-iter.
// ---------------------------------------------------------------------------
__global__ __launch_bounds__(256, 2) void out_gemm(const __bf16* __restrict__ Xa,
                                                   const __bf16* __restrict__ Wob,
                                                   const float* __restrict__ bo,
                                                   float* __restrict__ Out) {
  const int i0 = blockIdx.x << 6, j0 = blockIdx.y << 7;
  __shared__ __bf16 As[64][72];
  __shared__ __bf16 Bs[128][72];

  const int tid = threadIdx.x;
  const int wv = tid >> 6, lane = tid & 63;
  const int l = lane & 15, seg = lane >> 4;
  const int sr = tid >> 2, sc = (tid & 3) << 4;

  f32x4 O[2][4];                       // [j][r4]; unit u = wv + 4*j
#pragma unroll
  for (int j = 0; j < 2; ++j)
#pragma unroll
    for (int r4 = 0; r4 < 4; ++r4) O[j][r4] = (f32x4){0.f, 0.f, 0.f, 0.f};

  bf16x8 ar0, ar1, br[2][2];
#define LOADOUT(K0)                                                          \
  {                                                                          \
    const __bf16* xp = Xa + (size_t)(i0 + sr) * 512 + (K0) + sc;             \
    ar0 = *(const bf16x8*)xp; ar1 = *(const bf16x8*)(xp + 8);                \
    _Pragma("unroll")                                                        \
    for (int ps = 0; ps < 2; ++ps) {                                         \
      const __bf16* wp = Wob + (size_t)(j0 + ps * 64 + sr) * 512 + (K0) + sc;\
      br[ps][0] = *(const bf16x8*)wp; br[ps][1] = *(const bf16x8*)(wp + 8);  \
    }                                                                        \
  }

  LOADOUT(0)
  for (int k0 = 0; k0 < 512; k0 += 64) {
    __syncthreads();
    *(bf16x8*)&As[sr][sc]     = ar0;
    *(bf16x8*)&As[sr][sc + 8] = ar1;
#pragma unroll
    for (int ps = 0; ps < 2; ++ps) {
      *(bf16x8*)&Bs[ps * 64 + sr][sc]     = br[ps][0];
      *(bf16x8*)&Bs[ps * 64 + sr][sc + 8] = br[ps][1];
    }
    __syncthreads();
    if (k0 < 448) LOADOUT(k0 + 64)

    bf16x8 a0[4], a1[4];
#pragma unroll
    for (int r4 = 0; r4 < 4; ++r4) {
      a0[r4] = *(const bf16x8*)&As[r4 * 16 + l][seg * 8];
      a1[r4] = *(const bf16x8*)&As[r4 * 16 + l][seg * 8 + 32];
    }
#pragma unroll
    for (int j = 0; j < 2; ++j) {
      const int u = wv + 4 * j;
      bf16x8 b0 = *(const bf16x8*)&Bs[u * 16 + l][seg * 8];
      bf16x8 b1 = *(const bf16x8*)&Bs[u * 16 + l][seg * 8 + 32];
#pragma unroll
      for (int r4 = 0; r4 < 4; ++r4) {
        O[j][r4] = __builtin_amdgcn_mfma_f32_16x16x32_bf16(a0[r4], b0, O[j][r4], 0, 0, 0);
        O[j][r4] = __builtin_amdgcn_mfma_f32_16x16x32_bf16(a1[r4], b1, O[j][r4], 0, 0, 0);
      }
    }
  }

#pragma unroll
  for (int j = 0; j < 2; ++j) {
    const int u = wv + 4 * j;
    const float bb = bo[j0 + u * 16 + l];
#pragma unroll
    for (int r4 = 0; r4 < 4; ++r4)
#pragma unroll
      for (int reg = 0; reg < 4; ++reg) {
        const int m = r4 * 16 + (seg << 2) + reg;
        Out[(size_t)(i0 + m) * 512 + j0 + u * 16 + l] = O[j][r4][reg] + bb;
      }
  }
}

// ---------------------------------------------------------------------------
extern "C" void kernel_launch(void* const* d_in, const int* in_sizes, int n_in,
                              void* d_out, int out_size, void* d_ws, size_t ws_size,
                              hipStream_t stream) {
  (void)in_sizes; (void)n_in; (void)out_size; (void)ws_size;
  const float* seq  = (const float*)d_in[0];
  const float* mask = (const float*)d_in[1];
  const int*   pos  = (const int*)d_in[2];
  const float* Wq = (const float*)d_in[4];
  const float* bq = (const float*)d_in[5];
  const float* Wk = (const float*)d_in[6];
  const float* bk = (const float*)d_in[7];
  const float* Wv = (const float*)d_in[8];
  const float* bv = (const float*)d_in[9];
  const float* Wo = (const float*)d_in[10];
  const float* bo = (const float*)d_in[11];
  float* out = (float*)d_out;

  char* base = (char*)d_ws;
  __bf16* att = (__bf16*)base;                     // 4 MB  (4096 x 512 bf16)
  __bf16* Qh  = (__bf16*)(base + ( 4u << 20));     // 4 MB
  __bf16* Kh  = (__bf16*)(base + ( 8u << 20));     // 4 MB
  __bf16* Vt  = (__bf16*)(base + (12u << 20));     // 4 MB  [nh][d][2048]
  __bf16* Wb  = (__bf16*)(base + (16u << 20));     // 1.5 MB
  __bf16* Wob = (__bf16*)(base + (18u << 20));     // 0.5 MB
  float* PartO  = (float*)(base + (23u << 20));    // 16*72*4096*4 = 18.9 MB
  float* PartP  = (float*)(base + (42u << 20));    // 16*72*64*4   = 295 KB
  float* PartA0 = (float*)(base + (43u << 20));    // 16*24*64*4   = 98 KB

  cvt_kernel<<<1024, 256, 0, stream>>>(Wq, Wk, Wv, Wo, Wb, Wob);
  qkv_gemm<<<dim3(64, 8), 256, 0, stream>>>(seq, Wb, bq, bk, bv, pos, Qh, Kh, Vt);
  attn_chunk<<<1280, 256, 0, stream>>>(Qh, Kh, Vt, mask, att, PartO, PartP, PartA0);
  combine_kernel<<<384, 256, 0, stream>>>(PartO, PartP, PartA0, Vt, att);
  out_gemm<<<dim3(64, 4), 256, 0, stream>>>(att, Wob, bo, out);
}